// Round 1
// baseline (990.575 us; speedup 1.0000x reference)
//
#include <hip/hip_runtime.h>

#define NUM_ITEM 500000
#define EMBED_DIM 64

// One 64-lane group per edge: lane l accumulates dimension l.
__global__ __launch_bounds__(256) void scatter_mean_accum(
    const float* __restrict__ user_embed,
    const int* __restrict__ edge_src,
    const int* __restrict__ edge_dst,
    float* __restrict__ sums,      // d_out, pre-zeroed: [NUM_ITEM, 64]
    float* __restrict__ counts,    // d_ws,  pre-zeroed: [NUM_ITEM]
    int num_edges)
{
    const int edges_per_block = blockDim.x >> 6;           // 4 for 256 threads
    const int edge = blockIdx.x * edges_per_block + (threadIdx.x >> 6);
    const int lane = threadIdx.x & 63;
    if (edge >= num_edges) return;

    const int s = edge_src[edge];
    const int d = edge_dst[edge];

    const float v = user_embed[(size_t)s * EMBED_DIM + lane];
    atomicAdd(&sums[(size_t)d * EMBED_DIM + lane], v);
    if (lane == 0) {
        atomicAdd(&counts[d], 1.0f);
    }
}

__global__ __launch_bounds__(256) void divide_by_count(
    float* __restrict__ out,
    const float* __restrict__ counts,
    int n)  // n = NUM_ITEM * EMBED_DIM
{
    const int idx = blockIdx.x * blockDim.x + threadIdx.x;
    if (idx >= n) return;
    const float c = counts[idx >> 6];   // EMBED_DIM == 64
    out[idx] = out[idx] / fmaxf(c, 1.0f);
}

extern "C" void kernel_launch(void* const* d_in, const int* in_sizes, int n_in,
                              void* d_out, int out_size, void* d_ws, size_t ws_size,
                              hipStream_t stream)
{
    const float* user_embed = (const float*)d_in[0];
    // d_in[1] = item_embed (unused by the reference's net computation)
    const int* edge_src = (const int*)d_in[2];
    const int* edge_dst = (const int*)d_in[3];
    const int num_edges = in_sizes[2];

    float* sums   = (float*)d_out;          // [NUM_ITEM, EMBED_DIM]
    float* counts = (float*)d_ws;           // [NUM_ITEM]

    // Harness poisons d_out/d_ws with 0xAA before every launch — zero them.
    hipMemsetAsync(d_out, 0, (size_t)NUM_ITEM * EMBED_DIM * sizeof(float), stream);
    hipMemsetAsync(d_ws, 0, (size_t)NUM_ITEM * sizeof(float), stream);

    // Scatter-accumulate: 64 lanes per edge.
    {
        const int threads = 256;
        const int edges_per_block = threads / 64;
        const int blocks = (num_edges + edges_per_block - 1) / edges_per_block;
        scatter_mean_accum<<<blocks, threads, 0, stream>>>(
            user_embed, edge_src, edge_dst, sums, counts, num_edges);
    }

    // Divide by max(count, 1).
    {
        const int n = NUM_ITEM * EMBED_DIM;
        const int threads = 256;
        const int blocks = (n + threads - 1) / threads;
        divide_by_count<<<blocks, threads, 0, stream>>>(sums, counts, n);
    }
}

// Round 2
// 939.736 us; speedup vs baseline: 1.0541x; 1.0541x over previous
//
#include <hip/hip_runtime.h>

#define NUM_ITEM 500000
#define EMBED_DIM 64

// ---------------- CSR pipeline kernels ----------------

// K2: histogram of edge_dst
__global__ __launch_bounds__(256) void histogram_dst(
    const int* __restrict__ edge_dst, int num_edges, int* __restrict__ counts)
{
    int e = blockIdx.x * blockDim.x + threadIdx.x;
    if (e >= num_edges) return;
    atomicAdd(&counts[edge_dst[e]], 1);
}

// K3: per-256-chunk sums of counts
__global__ __launch_bounds__(256) void block_sums(
    const int* __restrict__ counts, int n, int* __restrict__ partials)
{
    __shared__ int red[256];
    int i = blockIdx.x * 256 + threadIdx.x;
    red[threadIdx.x] = (i < n) ? counts[i] : 0;
    __syncthreads();
    for (int s = 128; s > 0; s >>= 1) {
        if (threadIdx.x < (unsigned)s) red[threadIdx.x] += red[threadIdx.x + s];
        __syncthreads();
    }
    if (threadIdx.x == 0) partials[blockIdx.x] = red[0];
}

// K4: single-block exclusive scan of partials (nb up to a few thousand)
__global__ __launch_bounds__(256) void scan_partials(int* __restrict__ partials, int nb)
{
    __shared__ int tmp[256];
    __shared__ int carry_s;
    if (threadIdx.x == 0) carry_s = 0;
    __syncthreads();
    for (int base = 0; base < nb; base += 256) {
        int i = base + threadIdx.x;
        int v = (i < nb) ? partials[i] : 0;
        tmp[threadIdx.x] = v;
        __syncthreads();
        for (int off = 1; off < 256; off <<= 1) {
            int t = (threadIdx.x >= (unsigned)off) ? tmp[threadIdx.x - off] : 0;
            __syncthreads();
            tmp[threadIdx.x] += t;
            __syncthreads();
        }
        int incl = tmp[threadIdx.x];
        int c = carry_s;
        if (i < nb) partials[i] = incl - v + c;   // exclusive + carry
        __syncthreads();
        if (threadIdx.x == 255) carry_s = c + tmp[255];  // chunk total
        __syncthreads();
    }
}

// K5: offsets[i] = partials[block] + local exclusive scan; cursor = offsets copy
__global__ __launch_bounds__(256) void make_offsets(
    const int* __restrict__ counts, const int* __restrict__ partials, int n,
    int* __restrict__ offsets, int* __restrict__ cursor)
{
    __shared__ int tmp[256];
    int i = blockIdx.x * 256 + threadIdx.x;
    int v = (i < n) ? counts[i] : 0;
    tmp[threadIdx.x] = v;
    __syncthreads();
    for (int off = 1; off < 256; off <<= 1) {
        int t = (threadIdx.x >= (unsigned)off) ? tmp[threadIdx.x - off] : 0;
        __syncthreads();
        tmp[threadIdx.x] += t;
        __syncthreads();
    }
    int excl = tmp[threadIdx.x] - v + partials[blockIdx.x];
    if (i < n) { offsets[i] = excl; cursor[i] = excl; }
}

// K6: scatter edge srcs into CSR buckets
__global__ __launch_bounds__(256) void scatter_csr(
    const int* __restrict__ edge_src, const int* __restrict__ edge_dst,
    int num_edges, int* __restrict__ cursor, int* __restrict__ csr_src)
{
    int e = blockIdx.x * blockDim.x + threadIdx.x;
    if (e >= num_edges) return;
    int d = edge_dst[e];
    int pos = atomicAdd(&cursor[d], 1);
    csr_src[pos] = edge_src[e];
}

// K7: one 64-lane wave per item; lane = embedding dim
__global__ __launch_bounds__(256) void gather_mean(
    const float* __restrict__ user_embed, const int* __restrict__ csr_src,
    const int* __restrict__ offsets, const int* __restrict__ counts,
    float* __restrict__ out, int n_items)
{
    int item = blockIdx.x * 4 + (threadIdx.x >> 6);
    int lane = threadIdx.x & 63;
    if (item >= n_items) return;
    int off = offsets[item];
    int cnt = counts[item];
    float sum = 0.f;
    for (int e = 0; e < cnt; ++e) {
        int s = csr_src[off + e];                   // wave-uniform broadcast load
        sum += user_embed[(size_t)s * EMBED_DIM + lane];
    }
    float denom = (cnt > 0) ? (float)cnt : 1.0f;
    out[(size_t)item * EMBED_DIM + lane] = sum / denom;
}

// ---------------- fallback (R1 atomic path) ----------------

__global__ __launch_bounds__(256) void scatter_mean_accum(
    const float* __restrict__ user_embed,
    const int* __restrict__ edge_src,
    const int* __restrict__ edge_dst,
    float* __restrict__ sums, float* __restrict__ counts, int num_edges)
{
    const int edge = blockIdx.x * (blockDim.x >> 6) + (threadIdx.x >> 6);
    const int lane = threadIdx.x & 63;
    if (edge >= num_edges) return;
    const int s = edge_src[edge];
    const int d = edge_dst[edge];
    atomicAdd(&sums[(size_t)d * EMBED_DIM + lane],
              user_embed[(size_t)s * EMBED_DIM + lane]);
    if (lane == 0) atomicAdd(&counts[d], 1.0f);
}

__global__ __launch_bounds__(256) void divide_by_count(
    float* __restrict__ out, const float* __restrict__ counts, int n)
{
    const int idx = blockIdx.x * blockDim.x + threadIdx.x;
    if (idx >= n) return;
    out[idx] = out[idx] / fmaxf(counts[idx >> 6], 1.0f);
}

// ---------------- launcher ----------------

extern "C" void kernel_launch(void* const* d_in, const int* in_sizes, int n_in,
                              void* d_out, int out_size, void* d_ws, size_t ws_size,
                              hipStream_t stream)
{
    const float* user_embed = (const float*)d_in[0];
    const int* edge_src = (const int*)d_in[2];
    const int* edge_dst = (const int*)d_in[3];
    const int num_edges = in_sizes[2];
    float* out = (float*)d_out;

    // ws layout: counts | offsets | cursor | partials(2048) | csr_src
    const int NB = (NUM_ITEM + 255) / 256;               // 1954
    const size_t counts_b   = (size_t)NUM_ITEM * 4;
    const size_t offsets_b  = (size_t)NUM_ITEM * 4;
    const size_t cursor_b   = (size_t)NUM_ITEM * 4;
    const size_t partials_b = 2048 * 4;
    const size_t csr_b      = (size_t)num_edges * 4;
    const size_t needed = counts_b + offsets_b + cursor_b + partials_b + csr_b;

    if (ws_size >= needed) {
        char* ws = (char*)d_ws;
        int* counts   = (int*)ws;                         ws += counts_b;
        int* offsets  = (int*)ws;                         ws += offsets_b;
        int* cursor   = (int*)ws;                         ws += cursor_b;
        int* partials = (int*)ws;                         ws += partials_b;
        int* csr_src  = (int*)ws;

        hipMemsetAsync(counts, 0, counts_b, stream);

        const int eb = (num_edges + 255) / 256;
        histogram_dst<<<eb, 256, 0, stream>>>(edge_dst, num_edges, counts);
        block_sums<<<NB, 256, 0, stream>>>(counts, NUM_ITEM, partials);
        scan_partials<<<1, 256, 0, stream>>>(partials, NB);
        make_offsets<<<NB, 256, 0, stream>>>(counts, partials, NUM_ITEM, offsets, cursor);
        scatter_csr<<<eb, 256, 0, stream>>>(edge_src, edge_dst, num_edges, cursor, csr_src);
        gather_mean<<<(NUM_ITEM + 3) / 4, 256, 0, stream>>>(
            user_embed, csr_src, offsets, counts, out, NUM_ITEM);
    } else {
        // fallback: atomic scatter (R1)
        float* counts = (float*)d_ws;
        hipMemsetAsync(d_out, 0, (size_t)NUM_ITEM * EMBED_DIM * sizeof(float), stream);
        hipMemsetAsync(d_ws, 0, (size_t)NUM_ITEM * sizeof(float), stream);
        const int blocks = (num_edges + 3) / 4;
        scatter_mean_accum<<<blocks, 256, 0, stream>>>(
            user_embed, edge_src, edge_dst, out, counts, num_edges);
        const int n = NUM_ITEM * EMBED_DIM;
        divide_by_count<<<(n + 255) / 256, 256, 0, stream>>>(out, counts, n);
    }
}